// Round 17
// baseline (154.530 us; speedup 1.0000x reference)
//
#include <hip/hip_runtime.h>
#include <hip/hip_bf16.h>
#include <cstdint>
#include <cstddef>

// ---------- types ----------
typedef __attribute__((ext_vector_type(4))) float f32x4;
typedef __attribute__((ext_vector_type(8))) short bf16x8;
typedef __attribute__((ext_vector_type(4))) int i32x4;
typedef void __attribute__((address_space(1)))* as1_void_p;
typedef void __attribute__((address_space(3)))* as3_void_p;

#define T_SEQ 2048
#define D_MODEL 2048
#define NUM_HEADS 32
#define NUM_KV 8
#define GROUPS 4
#define DK 64
#define WINDOW 512
#define BATCH 2

#define NEG_BIG (-30000.0f)

// fp32 -> bf16 round-to-nearest-even
__device__ __forceinline__ unsigned short f2b(float f) {
    unsigned int u = __builtin_bit_cast(unsigned int, f);
    u = (u + 0x7FFFu + ((u >> 16) & 1u)) >> 16;
    return (unsigned short)u;
}

// packed fp32x2 -> bf16x2 (single HW instruction; no builtin on gfx950)
__device__ __forceinline__ unsigned int cvtpk_bf16(float lo, float hi) {
    unsigned int r;
    asm("v_cvt_pk_bf16_f32 %0, %1, %2" : "=v"(r) : "v"(lo), "v"(hi));
    return r;
}

__device__ __forceinline__ void load_lds16(const void* g, void* l) {
    __builtin_amdgcn_global_load_lds((as1_void_p)(uintptr_t)g,
                                     (as3_void_p)(unsigned int)(uintptr_t)l,
                                     16, 0, 0);
}

// ---------- fused cast: all five fp32 inputs -> one contiguous bf16 region ----
#define CAST_N0 8388608
#define CAST_N1 12582912
#define CAST_N2 13631488
#define CAST_N3 14680064
#define CAST_N4 18874368
__global__ void cast_all_kernel(const float* __restrict__ x, const float* __restrict__ wq,
                                const float* __restrict__ wk, const float* __restrict__ wv,
                                const float* __restrict__ wo, unsigned short* __restrict__ dst) {
    int i = (blockIdx.x * blockDim.x + threadIdx.x) * 4;
    const int stride = gridDim.x * blockDim.x * 4;
    for (; i < CAST_N4; i += stride) {
        const float* src;
        int off;
        if (i < CAST_N0)      { src = x;  off = i; }
        else if (i < CAST_N1) { src = wq; off = i - CAST_N0; }
        else if (i < CAST_N2) { src = wk; off = i - CAST_N1; }
        else if (i < CAST_N3) { src = wv; off = i - CAST_N2; }
        else                  { src = wo; off = i - CAST_N3; }
        const float4 v = *(const float4*)(src + off);
        ushort4 o;
        o.x = f2b(v.x); o.y = f2b(v.y); o.z = f2b(v.z); o.w = f2b(v.w);
        *(ushort4*)(dst + i) = o;
    }
}

// ---------- RoPE cos/sin table: [T][32] ----------
__global__ void rope_table_kernel(float* __restrict__ ct, float* __restrict__ st) {
    int i = blockIdx.x * blockDim.x + threadIdx.x;  // T*32 = 65536 exact
    int t = i >> 5, j = i & 31;
    const float kln = 0.28782313662425556f;  // ln(10000)/32
    float inv = __expf(-(float)j * kln);
    if (j == 0) inv = 1.0f;
    float ang = (float)t * inv;
    float s, c;
    sincosf(ang, &s, &c);
    ct[i] = c; st[i] = s;
}

// ============================================================================
// GEMM cores (R16-verified): ring-4 LDS, distance-3 prefetch, counted vmcnt,
// supertile XCD-affinity decode. Change this round: launch_bounds(512,4) on
// qkv (2 blocks/CU residency; 64KB LDS x2 fits).
// ============================================================================

// ---------- QKV GEMM (128x128, 8 waves 4Mx2N) + fused RoPE/relayout ---------
// Logical grid 32(tile_m) x 24(tile_n); 1-D launch 768 with supertile decode.
__global__ __launch_bounds__(512, 4) void gemm_qkv_rope(
    const unsigned short* __restrict__ A, const unsigned short* __restrict__ Bw,
    const float* __restrict__ ct, const float* __restrict__ st,
    unsigned short* __restrict__ Qb, unsigned short* __restrict__ Kb,
    unsigned short* __restrict__ Vt) {
    __shared__ __align__(16) unsigned short lds[32768];  // 64KB: 4 x (A4096 + B4096)
    // supertile decode: xcd owns tile_m band [4*xcd, 4*xcd+4), walks 6 B-slices
    const int bid = blockIdx.x;
    const int xcd = bid & 7;
    const int l = bid >> 3;            // 0..95
    const int stl = l >> 4;            // 0..5 supertile column
    const int w = l & 15;
    const int tmD = xcd * 4 + (w >> 2);    // 0..31
    const int tnD = stl * 4 + (w & 3);     // 0..23

    const int tid = threadIdx.x;
    const int lane = tid & 63;
    const int wid = tid >> 6;
    const int wr = wid >> 1, wc = wid & 1;   // 4M x 2N
    const int lrow = lane & 15;
    const int g = lane >> 4;
    const int tile_m = tmD, tile_n = tnD;
    const int arow = tile_m * 128;

    const int srow = tid >> 2, sslot = tid & 3;
    const int scol0 = (sslot ^ ((srow >> 1) & 3)) << 3;

    f32x4 acc[2][4] = {};

#define QSTAGE(BUF, KCOL)                                                      \
    {                                                                          \
        load_lds16(A + (size_t)(arow + srow) * 2048 + (KCOL) + scol0,          \
                   (char*)&lds[(BUF) * 8192] + tid * 16);                      \
        load_lds16(Bw + (size_t)(tnD * 128 + srow) * 2048 + (KCOL) + scol0,    \
                   (char*)&lds[(BUF) * 8192 + 4096] + tid * 16);               \
    }

    QSTAGE(0, 0) QSTAGE(1, 32) QSTAGE(2, 64)
    asm volatile("s_waitcnt vmcnt(4)" ::: "memory");
    __builtin_amdgcn_sched_barrier(0);
    __builtin_amdgcn_s_barrier();

    for (int t = 0; t < 64; ++t) {
        const int cb = (t & 3) * 8192;
        const int sb = (t + 3) & 3;
        bf16x8 af[2], bfr[4];
#pragma unroll
        for (int m = 0; m < 2; ++m) {
            const int R = wr * 32 + m * 16 + lrow;
            af[m] = *(const bf16x8*)&lds[cb + R * 32 + ((g ^ ((R >> 1) & 3)) << 3)];
        }
#pragma unroll
        for (int n = 0; n < 4; ++n) {
            const int R = wc * 64 + n * 16 + lrow;
            bfr[n] = *(const bf16x8*)&lds[cb + 4096 + R * 32 + ((g ^ ((R >> 1) & 3)) << 3)];
        }
        if (t + 3 < 64) QSTAGE(sb, (t + 3) * 32)
        __builtin_amdgcn_s_barrier();
        asm volatile("s_waitcnt lgkmcnt(0)" ::: "memory");
        __builtin_amdgcn_sched_barrier(0);
        __builtin_amdgcn_s_setprio(1);
#pragma unroll
        for (int m = 0; m < 2; ++m)
#pragma unroll
            for (int n = 0; n < 4; ++n)
                acc[m][n] = __builtin_amdgcn_mfma_f32_16x16x32_bf16(af[m], bfr[n], acc[m][n], 0, 0, 0);
        __builtin_amdgcn_s_setprio(0);
        if (t < 63) { asm volatile("s_waitcnt vmcnt(4)" ::: "memory"); }
        else        { asm volatile("s_waitcnt vmcnt(0)" ::: "memory"); }
        __builtin_amdgcn_sched_barrier(0);
        __builtin_amdgcn_s_barrier();
    }
#undef QSTAGE

    // ---- fused epilogue (wave owns 64-col head block) ----
    const int hcol = tile_n * 2 + wc;     // 0..47
#pragma unroll
    for (int m = 0; m < 2; ++m) {
        const int row0 = tile_m * 128 + wr * 32 + m * 16 + g * 4;
        const int bb = row0 >> 11;
        const int t0 = row0 & 2047;
        if (hcol < 40) {
            const bool isQ = (hcol < 32);
            const float sc = isQ ? 0.125f : 1.0f;
            unsigned short* base = isQ
                ? (Qb + ((size_t)(bb * NUM_HEADS + hcol) * T_SEQ) * 64)
                : (Kb + ((size_t)(bb * NUM_KV + (hcol - 32)) * T_SEQ) * 64);
#pragma unroll
            for (int r = 0; r < 4; ++r) {
                const int t = t0 + r;
                unsigned short* dst = base + (size_t)t * 64;
#pragma unroll
                for (int n = 0; n < 2; ++n) {
                    const int j = n * 16 + lrow;
                    const float c = ct[t * 32 + j], s = st[t * 32 + j];
                    const float v0 = acc[m][n][r], v1 = acc[m][n + 2][r];
                    dst[j]      = f2b((v0 * c - v1 * s) * sc);
                    dst[j + 32] = f2b((v1 * c + v0 * s) * sc);
                }
            }
        } else {
            const int vh = hcol - 40;
            const int chunk = t0 >> 5, tk = t0 & 31;
            unsigned short* cbase = Vt + ((size_t)(bb * NUM_KV + vh) * 64 + chunk) * 2048 + tk;
#pragma unroll
            for (int n = 0; n < 4; ++n) {
                const int d = n * 16 + lrow;
                unsigned int u0 = cvtpk_bf16(acc[m][n][0], acc[m][n][1]);
                unsigned int u1 = cvtpk_bf16(acc[m][n][2], acc[m][n][3]);
                uint2 val; val.x = u0; val.y = u1;
                *(uint2*)(cbase + d * 32) = val;
            }
        }
    }
}

// ---------- out-proj GEMM (128x256, 8 waves 2Mx4N): fp32 out ----------------
__global__ __launch_bounds__(512, 2) void gemm_bf16_nt(
    const unsigned short* __restrict__ A, const unsigned short* __restrict__ B,
    float* __restrict__ C) {
    __shared__ __align__(16) unsigned short lds[49152];  // 96KB: 4 x (A4096 + B8192)
    const int bid = blockIdx.x;
    const int xcd = bid & 7;
    const int l = bid >> 3;            // 0..31
    const int stl = l >> 4;            // 0..1
    const int w = l & 15;
    const int tmD = xcd * 4 + (w >> 2);    // 0..31
    const int tnD = stl * 4 + (w & 3);     // 0..7

    const int tid = threadIdx.x;
    const int lane = tid & 63;
    const int wid = tid >> 6;
    const int wr = wid >> 2, wc = wid & 3;   // 2M x 4N
    const int lrow = lane & 15;
    const int g = lane >> 4;
    const int tile_m = tmD, tile_n = tnD;
    const int arow = tile_m * 128, brow = tile_n * 256;

    const int srow = tid >> 2, sslot = tid & 3;
    const int scol = (sslot ^ ((srow >> 1) & 3)) << 3;

    f32x4 acc[4][4] = {};

#define OSTAGE(BUF, KCOL)                                                      \
    {                                                                          \
        load_lds16(A + (size_t)(arow + srow) * 2048 + (KCOL) + scol,           \
                   (char*)&lds[(BUF) * 12288] + tid * 16);                     \
        _Pragma("unroll") for (int u = 0; u < 2; ++u) {                        \
            const int gi = u * 512 + tid;                                      \
            const int br_ = gi >> 2, bs_ = gi & 3;                             \
            const int bc_ = (bs_ ^ ((br_ >> 1) & 3)) << 3;                     \
            load_lds16(B + (size_t)(brow + br_) * 2048 + (KCOL) + bc_,         \
                       (char*)&lds[(BUF) * 12288 + 4096] + gi * 16);           \
        }                                                                      \
    }

    OSTAGE(0, 0) OSTAGE(1, 32) OSTAGE(2, 64)
    asm volatile("s_waitcnt vmcnt(6)" ::: "memory");
    __builtin_amdgcn_sched_barrier(0);
    __builtin_amdgcn_s_barrier();

    for (int t = 0; t < 64; ++t) {
        const int cb = (t & 3) * 12288;
        const int sb = (t + 3) & 3;
        bf16x8 af[4], bfr[4];
#pragma unroll
        for (int m = 0; m < 4; ++m) {
            const int R = wr * 64 + m * 16 + lrow;
            af[m] = *(const bf16x8*)&lds[cb + R * 32 + ((g ^ ((R >> 1) & 3)) << 3)];
        }
#pragma unroll
        for (int n = 0; n < 4; ++n) {
            const int R = wc * 64 + n * 16 + lrow;
            bfr[n] = *(const bf16x8*)&lds[cb + 4096 + R * 32 + ((g ^ ((R >> 1) & 3)) << 3)];
        }
        if (t + 3 < 64) OSTAGE(sb, (t + 3) * 32)
        __builtin_amdgcn_s_barrier();
        asm volatile("s_waitcnt lgkmcnt(0)" ::: "memory");
        __builtin_amdgcn_sched_barrier(0);
        __builtin_amdgcn_s_setprio(1);
#pragma unroll
        for (int m = 0; m < 4; ++m)
#pragma unroll
            for (int n = 0; n < 4; ++n)
                acc[m][n] = __builtin_amdgcn_mfma_f32_16x16x32_bf16(af[m], bfr[n], acc[m][n], 0, 0, 0);
        __builtin_amdgcn_s_setprio(0);
        if (t < 63) { asm volatile("s_waitcnt vmcnt(6)" ::: "memory"); }
        else        { asm volatile("s_waitcnt vmcnt(0)" ::: "memory"); }
        __builtin_amdgcn_sched_barrier(0);
        __builtin_amdgcn_s_barrier();
    }
#undef OSTAGE

#pragma unroll
    for (int m = 0; m < 4; ++m)
#pragma unroll
        for (int n = 0; n < 4; ++n) {
            const int col = tile_n * 256 + wc * 64 + n * 16 + lrow;
#pragma unroll
            for (int r = 0; r < 4; ++r) {
                const int row = tile_m * 128 + wr * 64 + m * 16 + g * 4 + r;
                C[(size_t)row * 2048 + col] = acc[m][n][r];
            }
        }
}

// ---------- flash attention v9: LDS-shared K/V, ring-4 distance-3, 2 blk/CU -
// R14-verified structure; changes: ring-3 -> ring-4 (32KB, prefetch distance 3,
// steady vmcnt(2)) and launch_bounds(512,4) for 2 resident blocks/CU.
__global__ __launch_bounds__(512, 4) void attn_kernel(
    const unsigned short* __restrict__ Qb, const unsigned short* __restrict__ Kb,
    const unsigned short* __restrict__ Vt, unsigned short* __restrict__ Oout) {
    __shared__ __align__(16) unsigned short lds[16384];   // 4 x (K 2048 + V 2048)
    const int tid = threadIdx.x;
    const int lane = tid & 63;
    const int wv = tid >> 6;
    const int g4 = wv & 3;             // head within GQA group
    const int tile = wv >> 2;          // 0: rows q0A.., 1: rows q0A+16..
    const int bid = blockIdx.x;
    const int kvh = bid & 7;
    const int b = (bid >> 3) & 1;
    const int band = 63 - (bid >> 4);  // heavy-first
    const int q0A = band * 32;
    const int q0w = q0A + tile * 16;
    const int h = kvh * 4 + g4;

    const int lq = lane & 15;
    const int g = lane >> 4;
    const int kq8 = g * 8;
    const int q = q0w + lq;

    const unsigned short* Qrow = Qb + ((size_t)((b * NUM_HEADS + h) * T_SEQ) + q) * 64;
    const bf16x8 qf0 = *(const bf16x8*)(Qrow + kq8);
    const bf16x8 qf1 = *(const bf16x8*)(Qrow + 32 + kq8);

    f32x4 acc[4] = {};
    float lrun = 0.0f;

    int kc_lo = q0A - (WINDOW - 1);
    if (kc_lo < 0) kc_lo = 0;
    kc_lo &= ~31;
    const int N = ((q0A - kc_lo) >> 5) + 1;   // chunks, 1..17

    const unsigned short* Kg = Kb + (size_t)(b * NUM_KV + kvh) * T_SEQ * 64
                                  + (size_t)kc_lo * 64;
    const unsigned short* Vg = Vt + (size_t)(b * NUM_KV + kvh) * 64 * T_SEQ
                                  + (size_t)(kc_lo >> 5) * 2048;

    const int perm = (lq >> 2) * 8 + (lq & 3);
#define SWZK(r) (((r & 3) | ((r >> 3) << 2)) & 7)
    const int koff0 = perm * 64 + ((g ^ SWZK(perm)) << 3);
    const int koff1 = perm * 64 + (((4 + g) ^ SWZK(perm)) << 3);
    const int perm4 = perm + 4;
    const int koff2 = perm4 * 64 + ((g ^ SWZK(perm4)) << 3);
    const int koff3 = perm4 * 64 + (((4 + g) ^ SWZK(perm4)) << 3);
    int voff[4];
#pragma unroll
    for (int nd = 0; nd < 4; ++nd)
        voff[nd] = 2048 + (nd * 16 + lq) * 32 + ((g ^ ((lq >> 1) & 3)) << 3);

#define STAGE(T, BUF)                                                          \
    {                                                                          \
        if (tid < 256) {                                                       \
            const int row_ = tid >> 3, ps = tid & 7;                           \
            const int ls = ps ^ SWZK(row_);                                    \
            load_lds16(Kg + (size_t)(T) * 2048 + row_ * 64 + ls * 8,           \
                       (char*)lds + (BUF) * 8192 + tid * 16);                  \
        } else {                                                               \
            const int gi = tid - 256;                                          \
            const int row_ = gi >> 2, ps = gi & 3;                             \
            const int ls = ps ^ ((row_ >> 1) & 3);                             \
            load_lds16(Vg + (size_t)(T) * 2048 + row_ * 32 + ls * 8,           \
                       (char*)lds + (BUF) * 8192 + 4096 + gi * 16);            \
        }                                                                      \
    }

    STAGE(0, 0)
    if (N > 1) STAGE(1, 1)
    if (N > 2) STAGE(2, 2)
    if (N > 2)      { asm volatile("s_waitcnt vmcnt(2)" ::: "memory"); }
    else if (N > 1) { asm volatile("s_waitcnt vmcnt(1)" ::: "memory"); }
    else            { asm volatile("s_waitcnt vmcnt(0)" ::: "memory"); }
    __builtin_amdgcn_sched_barrier(0);
    __builtin_amdgcn_s_barrier();

    for (int t = 0; t < N; ++t) {
        const int kb = (t & 3) * 4096;
        bf16x8 kf[4], vf[4];
        kf[0] = *(const bf16x8*)&lds[kb + koff0];
        kf[1] = *(const bf16x8*)&lds[kb + koff1];
        kf[2] = *(const bf16x8*)&lds[kb + koff2];
        kf[3] = *(const bf16x8*)&lds[kb + koff3];
#pragma unroll
        for (int nd = 0; nd < 4; ++nd) vf[nd] = *(const bf16x8*)&lds[kb + voff[nd]];
        if (t + 3 < N) STAGE(t + 3, (t + 3) & 3)
        asm volatile("s_waitcnt lgkmcnt(0)" ::: "memory");
        __builtin_amdgcn_sched_barrier(0);

        const int kc = kc_lo + t * 32;
        f32x4 st2[2] = {};
        st2[0] = __builtin_amdgcn_mfma_f32_16x16x32_bf16(kf[0], qf0, st2[0], 0, 0, 0);
        st2[0] = __builtin_amdgcn_mfma_f32_16x16x32_bf16(kf[1], qf1, st2[0], 0, 0, 0);
        st2[1] = __builtin_amdgcn_mfma_f32_16x16x32_bf16(kf[2], qf0, st2[1], 0, 0, 0);
        st2[1] = __builtin_amdgcn_mfma_f32_16x16x32_bf16(kf[3], qf1, st2[1], 0, 0, 0);

        float s8[8];
#pragma unroll
        for (int tt = 0; tt < 2; ++tt)
#pragma unroll
            for (int r = 0; r < 4; ++r) s8[tt * 4 + r] = st2[tt][r];

        if (kc < q0w - 496 || kc > q0w - 31) {
#pragma unroll
            for (int i = 0; i < 8; ++i) {
                const int key = kc + g * 8 + ((i >> 2) << 2) + (i & 3);
                const int dist = q - key;
                if (dist < 0 || dist >= WINDOW) s8[i] = NEG_BIG;
            }
        }

        float p8[8];
        float ps = 0.0f;
#pragma unroll
        for (int i = 0; i < 8; ++i) {
            p8[i] = __expf(s8[i]);
            ps += p8[i];
        }
        lrun += ps;

        i32x4 pwi;
        pwi[0] = (int)cvtpk_bf16(p8[0], p8[1]);
        pwi[1] = (int)cvtpk_bf16(p8[2], p8[3]);
        pwi[2] = (int)cvtpk_bf16(p8[4], p8[5]);
        pwi[3] = (int)cvtpk_bf16(p8[6], p8[7]);
        const bf16x8 pw = __builtin_bit_cast(bf16x8, pwi);

#pragma unroll
        for (int nd = 0; nd < 4; ++nd)
            acc[nd] = __builtin_amdgcn_mfma_f32_16x16x32_bf16(vf[nd], pw, acc[nd], 0, 0, 0);

        if (t + 1 < N) {
            if (t + 3 < N)      { asm volatile("s_waitcnt vmcnt(2)" ::: "memory"); }
            else if (t + 2 < N) { asm volatile("s_waitcnt vmcnt(1)" ::: "memory"); }
            else                { asm volatile("s_waitcnt vmcnt(0)" ::: "memory"); }
            __builtin_amdgcn_sched_barrier(0);
            __builtin_amdgcn_s_barrier();
        }
    }
#undef STAGE
#undef SWZK

    lrun += __shfl_xor(lrun, 16);
    lrun += __shfl_xor(lrun, 32);

    const float inv = 1.0f / lrun;
#pragma unroll
    for (int nd = 0; nd < 4; ++nd) {
        unsigned int u0 = cvtpk_bf16(acc[nd][0] * inv, acc[nd][1] * inv);
        unsigned int u1 = cvtpk_bf16(acc[nd][2] * inv, acc[nd][3] * inv);
        unsigned short* dst = Oout + ((size_t)(b * T_SEQ + q)) * D_MODEL + h * 64 + nd * 16 + g * 4;
        uint2 val; val.x = u0; val.y = u1;
        *(uint2*)dst = val;
    }
}

// ---------- launch ----------
extern "C" void kernel_launch(void* const* d_in, const int* in_sizes, int n_in,
                              void* d_out, int out_size, void* d_ws, size_t ws_size,
                              hipStream_t stream) {
    const float* x = (const float*)d_in[0];
    const float* Wq = (const float*)d_in[1];
    const float* Wk = (const float*)d_in[2];
    const float* Wv = (const float*)d_in[3];
    const float* Wo = (const float*)d_in[4];
    float* out = (float*)d_out;

    char* ws = (char*)d_ws;
    size_t off = 0;
    auto alloc = [&](size_t bytes) -> char* {
        char* p = ws + off;
        off += (bytes + 255) & ~(size_t)255;
        return p;
    };
    // NOTE: xb, wcat, wob MUST stay contiguous in this order (cast_all_kernel
    // writes them as one linear region).
    unsigned short* xb   = (unsigned short*)alloc(8388608ull * 2);   // x bf16
    unsigned short* wcat = (unsigned short*)alloc(6291456ull * 2);   // [Wq;Wk;Wv]
    unsigned short* wob  = (unsigned short*)alloc(4194304ull * 2);   // Wo
    unsigned short* qb   = (unsigned short*)alloc(8388608ull * 2);   // [B][32][T][64]
    unsigned short* kb   = (unsigned short*)alloc(2097152ull * 2);   // [B][8][T][64]
    unsigned short* vt   = (unsigned short*)alloc(2097152ull * 2);   // [B][8][64 chunks][64][32]
    unsigned short* attn = (unsigned short*)alloc(8388608ull * 2);   // [4096][2048]
    float* ct            = (float*)alloc(65536ull * 4);
    float* st            = (float*)alloc(65536ull * 4);

    cast_all_kernel<<<2048, 256, 0, stream>>>(x, Wq, Wk, Wv, Wo, xb);
    rope_table_kernel<<<256, 256, 0, stream>>>(ct, st);

    // QKV projection + fused RoPE/relayout: [4096,2048] x [3072,2048]^T
    gemm_qkv_rope<<<768, 512, 0, stream>>>(xb, wcat, ct, st, qb, kb, vt);

    attn_kernel<<<1024, 512, 0, stream>>>(qb, kb, vt, attn);

    // output projection: [4096,2048] x [2048,2048]^T -> d_out fp32
    gemm_bf16_nt<<<256, 512, 0, stream>>>(attn, wob, out);
}

// Round 18
// 150.022 us; speedup vs baseline: 1.0300x; 1.0300x over previous
//
#include <hip/hip_runtime.h>
#include <hip/hip_bf16.h>
#include <cstdint>
#include <cstddef>

// ---------- types ----------
typedef __attribute__((ext_vector_type(4))) float f32x4;
typedef __attribute__((ext_vector_type(8))) short bf16x8;
typedef __attribute__((ext_vector_type(4))) int i32x4;
typedef void __attribute__((address_space(1)))* as1_void_p;
typedef void __attribute__((address_space(3)))* as3_void_p;

#define T_SEQ 2048
#define D_MODEL 2048
#define NUM_HEADS 32
#define NUM_KV 8
#define GROUPS 4
#define DK 64
#define WINDOW 512
#define BATCH 2

#define NEG_BIG (-30000.0f)

// fp32 -> bf16 round-to-nearest-even
__device__ __forceinline__ unsigned short f2b(float f) {
    unsigned int u = __builtin_bit_cast(unsigned int, f);
    u = (u + 0x7FFFu + ((u >> 16) & 1u)) >> 16;
    return (unsigned short)u;
}

// packed fp32x2 -> bf16x2 (single HW instruction; no builtin on gfx950)
__device__ __forceinline__ unsigned int cvtpk_bf16(float lo, float hi) {
    unsigned int r;
    asm("v_cvt_pk_bf16_f32 %0, %1, %2" : "=v"(r) : "v"(lo), "v"(hi));
    return r;
}

__device__ __forceinline__ void load_lds16(const void* g, void* l) {
    __builtin_amdgcn_global_load_lds((as1_void_p)(uintptr_t)g,
                                     (as3_void_p)(unsigned int)(uintptr_t)l,
                                     16, 0, 0);
}

// ---------- fused cast: all five fp32 inputs -> one contiguous bf16 region ----
#define CAST_N0 8388608
#define CAST_N1 12582912
#define CAST_N2 13631488
#define CAST_N3 14680064
#define CAST_N4 18874368
__global__ void cast_all_kernel(const float* __restrict__ x, const float* __restrict__ wq,
                                const float* __restrict__ wk, const float* __restrict__ wv,
                                const float* __restrict__ wo, unsigned short* __restrict__ dst) {
    int i = (blockIdx.x * blockDim.x + threadIdx.x) * 4;
    const int stride = gridDim.x * blockDim.x * 4;
    for (; i < CAST_N4; i += stride) {
        const float* src;
        int off;
        if (i < CAST_N0)      { src = x;  off = i; }
        else if (i < CAST_N1) { src = wq; off = i - CAST_N0; }
        else if (i < CAST_N2) { src = wk; off = i - CAST_N1; }
        else if (i < CAST_N3) { src = wv; off = i - CAST_N2; }
        else                  { src = wo; off = i - CAST_N3; }
        const float4 v = *(const float4*)(src + off);
        ushort4 o;
        o.x = f2b(v.x); o.y = f2b(v.y); o.z = f2b(v.z); o.w = f2b(v.w);
        *(ushort4*)(dst + i) = o;
    }
}

// ---------- RoPE cos/sin table: [T][32] ----------
__global__ void rope_table_kernel(float* __restrict__ ct, float* __restrict__ st) {
    int i = blockIdx.x * blockDim.x + threadIdx.x;  // T*32 = 65536 exact
    int t = i >> 5, j = i & 31;
    const float kln = 0.28782313662425556f;  // ln(10000)/32
    float inv = __expf(-(float)j * kln);
    if (j == 0) inv = 1.0f;
    float ang = (float)t * inv;
    float s, c;
    sincosf(ang, &s, &c);
    ct[i] = c; st[i] = s;
}

// ============================================================================
// QKV GEMM v3: 256x256 tile, 8 waves 2Mx4N, acc[8][4] (32 MFMA / 12 ds_reads
// per K-tile), ring-4 LDS (128KB, BK=32 slots), distance-3 prefetch, counted
// vmcnt(8), and ONE barrier + one lgkmcnt + one vmcnt per K-tile (R15 proved
// single-barrier safety: stage(t+3) targets buf(t-1), whose readers finished
// before the end-of-(t-1) barrier). Supertile XCD decode: xcd owns a 512-row
// A-panel (2MB) and walks 2-tile B-slices (2MB) -> 4MB/XCD = its L2.
// ============================================================================
__global__ __launch_bounds__(512, 2) void gemm_qkv_rope(
    const unsigned short* __restrict__ A, const unsigned short* __restrict__ Bw,
    const float* __restrict__ ct, const float* __restrict__ st,
    unsigned short* __restrict__ Qb, unsigned short* __restrict__ Kb,
    unsigned short* __restrict__ Vt) {
    __shared__ __align__(16) unsigned short lds[65536];  // 128KB: 4 x (A 16KB + B 16KB)
    // bijective supertile decode for grid 192 = 8 xcd x 24
    const int bid = blockIdx.x;
    const int xcd = bid & 7;
    const int l = bid >> 3;            // 0..23
    const int stl = l >> 2;            // 0..5
    const int w = l & 3;
    const int tile_m = xcd * 2 + (w >> 1);   // 0..15
    const int tile_n = stl * 2 + (w & 1);    // 0..11

    const int tid = threadIdx.x;
    const int lane = tid & 63;
    const int wid = tid >> 6;
    const int wr = wid >> 2, wc = wid & 3;   // 2M x 4N
    const int lrow = lane & 15;
    const int g = lane >> 4;
    const int arow = tile_m * 256, brow = tile_n * 256;

    f32x4 acc[8][4] = {};

#define QSTAGE(SRC, ROWBASE, KCOL, USHOFF)                                     \
    { _Pragma("unroll") for (int u = 0; u < 2; ++u) {                          \
        const int gi = u * 512 + tid;                                          \
        const int row_ = gi >> 2, sl_ = gi & 3;                                \
        const int sc_ = (sl_ ^ ((row_ >> 1) & 3)) << 3;                        \
        load_lds16(SRC + (size_t)((ROWBASE) + row_) * 2048 + (KCOL) + sc_,     \
                   (char*)&lds[USHOFF] + gi * 16); } }

    QSTAGE(A, arow, 0,  0)     QSTAGE(Bw, brow, 0,  8192)
    QSTAGE(A, arow, 32, 16384) QSTAGE(Bw, brow, 32, 24576)
    QSTAGE(A, arow, 64, 32768) QSTAGE(Bw, brow, 64, 40960)
    asm volatile("s_waitcnt vmcnt(8)" ::: "memory");   // tile0's 4 loads landed
    __builtin_amdgcn_sched_barrier(0);
    __builtin_amdgcn_s_barrier();

    for (int t = 0; t < 64; ++t) {
        const int cb = (t & 3) * 16384;
        const int sb = ((t + 3) & 3) * 16384;
        bf16x8 af[8], bfr[4];
#pragma unroll
        for (int m = 0; m < 8; ++m) {
            const int R = wr * 128 + m * 16 + lrow;
            af[m] = *(const bf16x8*)&lds[cb + R * 32 + ((g ^ ((R >> 1) & 3)) << 3)];
        }
#pragma unroll
        for (int n = 0; n < 4; ++n) {
            const int R = wc * 64 + n * 16 + lrow;
            bfr[n] = *(const bf16x8*)&lds[cb + 8192 + R * 32 + ((g ^ ((R >> 1) & 3)) << 3)];
        }
        if (t + 3 < 64) {
            QSTAGE(A, arow, (t + 3) * 32, sb)
            QSTAGE(Bw, brow, (t + 3) * 32, sb + 8192)
        }
        asm volatile("s_waitcnt lgkmcnt(0)" ::: "memory");
        __builtin_amdgcn_sched_barrier(0);
        __builtin_amdgcn_s_setprio(1);
#pragma unroll
        for (int m = 0; m < 8; ++m)
#pragma unroll
            for (int n = 0; n < 4; ++n)
                acc[m][n] = __builtin_amdgcn_mfma_f32_16x16x32_bf16(af[m], bfr[n], acc[m][n], 0, 0, 0);
        __builtin_amdgcn_s_setprio(0);
        // counted wait: leave {t+2, t+3} in flight => t+1 landed
        if (t < 61)      { asm volatile("s_waitcnt vmcnt(8)" ::: "memory"); }
        else if (t == 61){ asm volatile("s_waitcnt vmcnt(4)" ::: "memory"); }
        else             { asm volatile("s_waitcnt vmcnt(0)" ::: "memory"); }
        __builtin_amdgcn_sched_barrier(0);
        __builtin_amdgcn_s_barrier();
    }
#undef QSTAGE

    // ---- fused epilogue: hcol = tile_n*4 + wc (64-col head block per wave) --
    const int hcol = tile_n * 4 + wc;     // 0..47
#pragma unroll
    for (int m = 0; m < 8; ++m) {
        const int row0 = tile_m * 256 + wr * 128 + m * 16 + g * 4;
        const int bb = row0 >> 11;
        const int t0 = row0 & 2047;
        if (hcol < 40) {
            const bool isQ = (hcol < 32);
            const float sc = isQ ? 0.125f : 1.0f;
            unsigned short* base = isQ
                ? (Qb + ((size_t)(bb * NUM_HEADS + hcol) * T_SEQ) * 64)
                : (Kb + ((size_t)(bb * NUM_KV + (hcol - 32)) * T_SEQ) * 64);
#pragma unroll
            for (int r = 0; r < 4; ++r) {
                const int t = t0 + r;
                unsigned short* dst = base + (size_t)t * 64;
#pragma unroll
                for (int n = 0; n < 2; ++n) {
                    const int j = n * 16 + lrow;
                    const float c = ct[t * 32 + j], s = st[t * 32 + j];
                    const float v0 = acc[m][n][r], v1 = acc[m][n + 2][r];
                    dst[j]      = f2b((v0 * c - v1 * s) * sc);
                    dst[j + 32] = f2b((v1 * c + v0 * s) * sc);
                }
            }
        } else {
            const int vh = hcol - 40;
            const int chunk = t0 >> 5, tk = t0 & 31;
            unsigned short* cbase = Vt + ((size_t)(bb * NUM_KV + vh) * 64 + chunk) * 2048 + tk;
#pragma unroll
            for (int n = 0; n < 4; ++n) {
                const int d = n * 16 + lrow;
                unsigned int u0 = cvtpk_bf16(acc[m][n][0], acc[m][n][1]);
                unsigned int u1 = cvtpk_bf16(acc[m][n][2], acc[m][n][3]);
                uint2 val; val.x = u0; val.y = u1;
                *(uint2*)(cbase + d * 32) = val;
            }
        }
    }
}

// ---------- out-proj GEMM (128x256, 8 waves 2Mx4N): fp32 out (R16 verified) --
__global__ __launch_bounds__(512, 2) void gemm_bf16_nt(
    const unsigned short* __restrict__ A, const unsigned short* __restrict__ B,
    float* __restrict__ C) {
    __shared__ __align__(16) unsigned short lds[49152];  // 96KB: 4 x (A4096 + B8192)
    const int bid = blockIdx.x;
    const int xcd = bid & 7;
    const int l = bid >> 3;            // 0..31
    const int stl = l >> 4;            // 0..1
    const int w = l & 15;
    const int tmD = xcd * 4 + (w >> 2);    // 0..31
    const int tnD = stl * 4 + (w & 3);     // 0..7

    const int tid = threadIdx.x;
    const int lane = tid & 63;
    const int wid = tid >> 6;
    const int wr = wid >> 2, wc = wid & 3;   // 2M x 4N
    const int lrow = lane & 15;
    const int g = lane >> 4;
    const int tile_m = tmD, tile_n = tnD;
    const int arow = tile_m * 128, brow = tile_n * 256;

    const int srow = tid >> 2, sslot = tid & 3;
    const int scol = (sslot ^ ((srow >> 1) & 3)) << 3;

    f32x4 acc[4][4] = {};

#define OSTAGE(BUF, KCOL)                                                      \
    {                                                                          \
        load_lds16(A + (size_t)(arow + srow) * 2048 + (KCOL) + scol,           \
                   (char*)&lds[(BUF) * 12288] + tid * 16);                     \
        _Pragma("unroll") for (int u = 0; u < 2; ++u) {                        \
            const int gi = u * 512 + tid;                                      \
            const int br_ = gi >> 2, bs_ = gi & 3;                             \
            const int bc_ = (bs_ ^ ((br_ >> 1) & 3)) << 3;                     \
            load_lds16(B + (size_t)(brow + br_) * 2048 + (KCOL) + bc_,         \
                       (char*)&lds[(BUF) * 12288 + 4096] + gi * 16);           \
        }                                                                      \
    }

    OSTAGE(0, 0) OSTAGE(1, 32) OSTAGE(2, 64)
    asm volatile("s_waitcnt vmcnt(6)" ::: "memory");
    __builtin_amdgcn_sched_barrier(0);
    __builtin_amdgcn_s_barrier();

    for (int t = 0; t < 64; ++t) {
        const int cb = (t & 3) * 12288;
        const int sb = (t + 3) & 3;
        bf16x8 af[4], bfr[4];
#pragma unroll
        for (int m = 0; m < 4; ++m) {
            const int R = wr * 64 + m * 16 + lrow;
            af[m] = *(const bf16x8*)&lds[cb + R * 32 + ((g ^ ((R >> 1) & 3)) << 3)];
        }
#pragma unroll
        for (int n = 0; n < 4; ++n) {
            const int R = wc * 64 + n * 16 + lrow;
            bfr[n] = *(const bf16x8*)&lds[cb + 4096 + R * 32 + ((g ^ ((R >> 1) & 3)) << 3)];
        }
        if (t + 3 < 64) OSTAGE(sb, (t + 3) * 32)
        __builtin_amdgcn_s_barrier();
        asm volatile("s_waitcnt lgkmcnt(0)" ::: "memory");
        __builtin_amdgcn_sched_barrier(0);
        __builtin_amdgcn_s_setprio(1);
#pragma unroll
        for (int m = 0; m < 4; ++m)
#pragma unroll
            for (int n = 0; n < 4; ++n)
                acc[m][n] = __builtin_amdgcn_mfma_f32_16x16x32_bf16(af[m], bfr[n], acc[m][n], 0, 0, 0);
        __builtin_amdgcn_s_setprio(0);
        if (t < 63) { asm volatile("s_waitcnt vmcnt(6)" ::: "memory"); }
        else        { asm volatile("s_waitcnt vmcnt(0)" ::: "memory"); }
        __builtin_amdgcn_sched_barrier(0);
        __builtin_amdgcn_s_barrier();
    }
#undef OSTAGE

#pragma unroll
    for (int m = 0; m < 4; ++m)
#pragma unroll
        for (int n = 0; n < 4; ++n) {
            const int col = tile_n * 256 + wc * 64 + n * 16 + lrow;
#pragma unroll
            for (int r = 0; r < 4; ++r) {
                const int row = tile_m * 128 + wr * 64 + m * 16 + g * 4 + r;
                C[(size_t)row * 2048 + col] = acc[m][n][r];
            }
        }
}

// ---------- flash attention v9 (R17 verified): LDS-shared K/V, ring-4 --------
__global__ __launch_bounds__(512, 4) void attn_kernel(
    const unsigned short* __restrict__ Qb, const unsigned short* __restrict__ Kb,
    const unsigned short* __restrict__ Vt, unsigned short* __restrict__ Oout) {
    __shared__ __align__(16) unsigned short lds[16384];   // 4 x (K 2048 + V 2048)
    const int tid = threadIdx.x;
    const int lane = tid & 63;
    const int wv = tid >> 6;
    const int g4 = wv & 3;             // head within GQA group
    const int tile = wv >> 2;          // 0: rows q0A.., 1: rows q0A+16..
    const int bid = blockIdx.x;
    const int kvh = bid & 7;
    const int b = (bid >> 3) & 1;
    const int band = 63 - (bid >> 4);  // heavy-first
    const int q0A = band * 32;
    const int q0w = q0A + tile * 16;
    const int h = kvh * 4 + g4;

    const int lq = lane & 15;
    const int g = lane >> 4;
    const int kq8 = g * 8;
    const int q = q0w + lq;

    const unsigned short* Qrow = Qb + ((size_t)((b * NUM_HEADS + h) * T_SEQ) + q) * 64;
    const bf16x8 qf0 = *(const bf16x8*)(Qrow + kq8);
    const bf16x8 qf1 = *(const bf16x8*)(Qrow + 32 + kq8);

    f32x4 acc[4] = {};
    float lrun = 0.0f;

    int kc_lo = q0A - (WINDOW - 1);
    if (kc_lo < 0) kc_lo = 0;
    kc_lo &= ~31;
    const int N = ((q0A - kc_lo) >> 5) + 1;   // chunks, 1..17

    const unsigned short* Kg = Kb + (size_t)(b * NUM_KV + kvh) * T_SEQ * 64
                                  + (size_t)kc_lo * 64;
    const unsigned short* Vg = Vt + (size_t)(b * NUM_KV + kvh) * 64 * T_SEQ
                                  + (size_t)(kc_lo >> 5) * 2048;

    const int perm = (lq >> 2) * 8 + (lq & 3);
#define SWZK(r) (((r & 3) | ((r >> 3) << 2)) & 7)
    const int koff0 = perm * 64 + ((g ^ SWZK(perm)) << 3);
    const int koff1 = perm * 64 + (((4 + g) ^ SWZK(perm)) << 3);
    const int perm4 = perm + 4;
    const int koff2 = perm4 * 64 + ((g ^ SWZK(perm4)) << 3);
    const int koff3 = perm4 * 64 + (((4 + g) ^ SWZK(perm4)) << 3);
    int voff[4];
#pragma unroll
    for (int nd = 0; nd < 4; ++nd)
        voff[nd] = 2048 + (nd * 16 + lq) * 32 + ((g ^ ((lq >> 1) & 3)) << 3);

#define STAGE(T, BUF)                                                          \
    {                                                                          \
        if (tid < 256) {                                                       \
            const int row_ = tid >> 3, ps = tid & 7;                           \
            const int ls = ps ^ SWZK(row_);                                    \
            load_lds16(Kg + (size_t)(T) * 2048 + row_ * 64 + ls * 8,           \
                       (char*)lds + (BUF) * 8192 + tid * 16);                  \
        } else {                                                               \
            const int gi = tid - 256;                                          \
            const int row_ = gi >> 2, ps = gi & 3;                             \
            const int ls = ps ^ ((row_ >> 1) & 3);                             \
            load_lds16(Vg + (size_t)(T) * 2048 + row_ * 32 + ls * 8,           \
                       (char*)lds + (BUF) * 8192 + 4096 + gi * 16);            \
        }                                                                      \
    }

    STAGE(0, 0)
    if (N > 1) STAGE(1, 1)
    if (N > 2) STAGE(2, 2)
    if (N > 2)      { asm volatile("s_waitcnt vmcnt(2)" ::: "memory"); }
    else if (N > 1) { asm volatile("s_waitcnt vmcnt(1)" ::: "memory"); }
    else            { asm volatile("s_waitcnt vmcnt(0)" ::: "memory"); }
    __builtin_amdgcn_sched_barrier(0);
    __builtin_amdgcn_s_barrier();

    for (int t = 0; t < N; ++t) {
        const int kb = (t & 3) * 4096;
        bf16x8 kf[4], vf[4];
        kf[0] = *(const bf16x8*)&lds[kb + koff0];
        kf[1] = *(const bf16x8*)&lds[kb + koff1];
        kf[2] = *(const bf16x8*)&lds[kb + koff2];
        kf[3] = *(const bf16x8*)&lds[kb + koff3];
#pragma unroll
        for (int nd = 0; nd < 4; ++nd) vf[nd] = *(const bf16x8*)&lds[kb + voff[nd]];
        if (t + 3 < N) STAGE(t + 3, (t + 3) & 3)
        asm volatile("s_waitcnt lgkmcnt(0)" ::: "memory");
        __builtin_amdgcn_sched_barrier(0);

        const int kc = kc_lo + t * 32;
        f32x4 st2[2] = {};
        st2[0] = __builtin_amdgcn_mfma_f32_16x16x32_bf16(kf[0], qf0, st2[0], 0, 0, 0);
        st2[0] = __builtin_amdgcn_mfma_f32_16x16x32_bf16(kf[1], qf1, st2[0], 0, 0, 0);
        st2[1] = __builtin_amdgcn_mfma_f32_16x16x32_bf16(kf[2], qf0, st2[1], 0, 0, 0);
        st2[1] = __builtin_amdgcn_mfma_f32_16x16x32_bf16(kf[3], qf1, st2[1], 0, 0, 0);

        float s8[8];
#pragma unroll
        for (int tt = 0; tt < 2; ++tt)
#pragma unroll
            for (int r = 0; r < 4; ++r) s8[tt * 4 + r] = st2[tt][r];

        if (kc < q0w - 496 || kc > q0w - 31) {
#pragma unroll
            for (int i = 0; i < 8; ++i) {
                const int key = kc + g * 8 + ((i >> 2) << 2) + (i & 3);
                const int dist = q - key;
                if (dist < 0 || dist >= WINDOW) s8[i] = NEG_BIG;
            }
        }

        float p8[8];
        float ps = 0.0f;
#pragma unroll
        for (int i = 0; i < 8; ++i) {
            p8[i] = __expf(s8[i]);
            ps += p8[i];
        }
        lrun += ps;

        i32x4 pwi;
        pwi[0] = (int)cvtpk_bf16(p8[0], p8[1]);
        pwi[1] = (int)cvtpk_bf16(p8[2], p8[3]);
        pwi[2] = (int)cvtpk_bf16(p8[4], p8[5]);
        pwi[3] = (int)cvtpk_bf16(p8[6], p8[7]);
        const bf16x8 pw = __builtin_bit_cast(bf16x8, pwi);

#pragma unroll
        for (int nd = 0; nd < 4; ++nd)
            acc[nd] = __builtin_amdgcn_mfma_f32_16x16x32_bf16(vf[nd], pw, acc[nd], 0, 0, 0);

        if (t + 1 < N) {
            if (t + 3 < N)      { asm volatile("s_waitcnt vmcnt(2)" ::: "memory"); }
            else if (t + 2 < N) { asm volatile("s_waitcnt vmcnt(1)" ::: "memory"); }
            else                { asm volatile("s_waitcnt vmcnt(0)" ::: "memory"); }
            __builtin_amdgcn_sched_barrier(0);
            __builtin_amdgcn_s_barrier();
        }
    }
#undef STAGE
#undef SWZK

    lrun += __shfl_xor(lrun, 16);
    lrun += __shfl_xor(lrun, 32);

    const float inv = 1.0f / lrun;
#pragma unroll
    for (int nd = 0; nd < 4; ++nd) {
        unsigned int u0 = cvtpk_bf16(acc[nd][0] * inv, acc[nd][1] * inv);
        unsigned int u1 = cvtpk_bf16(acc[nd][2] * inv, acc[nd][3] * inv);
        unsigned short* dst = Oout + ((size_t)(b * T_SEQ + q)) * D_MODEL + h * 64 + nd * 16 + g * 4;
        uint2 val; val.x = u0; val.y = u1;
        *(uint2*)dst = val;
    }
}

// ---------- launch ----------
extern "C" void kernel_launch(void* const* d_in, const int* in_sizes, int n_in,
                              void* d_out, int out_size, void* d_ws, size_t ws_size,
                              hipStream_t stream) {
    const float* x = (const float*)d_in[0];
    const float* Wq = (const float*)d_in[1];
    const float* Wk = (const float*)d_in[2];
    const float* Wv = (const float*)d_in[3];
    const float* Wo = (const float*)d_in[4];
    float* out = (float*)d_out;

    char* ws = (char*)d_ws;
    size_t off = 0;
    auto alloc = [&](size_t bytes) -> char* {
        char* p = ws + off;
        off += (bytes + 255) & ~(size_t)255;
        return p;
    };
    // NOTE: xb, wcat, wob MUST stay contiguous in this order (cast_all_kernel
    // writes them as one linear region).
    unsigned short* xb   = (unsigned short*)alloc(8388608ull * 2);   // x bf16
    unsigned short* wcat = (unsigned short*)alloc(6291456ull * 2);   // [Wq;Wk;Wv]
    unsigned short* wob  = (unsigned short*)alloc(4194304ull * 2);   // Wo
    unsigned short* qb   = (unsigned short*)alloc(8388608ull * 2);   // [B][32][T][64]
    unsigned short* kb   = (unsigned short*)alloc(2097152ull * 2);   // [B][8][T][64]
    unsigned short* vt   = (unsigned short*)alloc(2097152ull * 2);   // [B][8][64 chunks][64][32]
    unsigned short* attn = (unsigned short*)alloc(8388608ull * 2);   // [4096][2048]
    float* ct            = (float*)alloc(65536ull * 4);
    float* st            = (float*)alloc(65536ull * 4);

    cast_all_kernel<<<2048, 256, 0, stream>>>(x, Wq, Wk, Wv, Wo, xb);
    rope_table_kernel<<<256, 256, 0, stream>>>(ct, st);

    // QKV projection + fused RoPE/relayout: [4096,2048] x [3072,2048]^T
    gemm_qkv_rope<<<192, 512, 0, stream>>>(xb, wcat, ct, st, qb, kb, vt);

    attn_kernel<<<1024, 512, 0, stream>>>(qb, kb, vt, attn);

    // output projection: [4096,2048] x [2048,2048]^T -> d_out fp32
    gemm_bf16_nt<<<256, 512, 0, stream>>>(attn, wob, out);
}

// Round 19
// 148.270 us; speedup vs baseline: 1.0422x; 1.0118x over previous
//
#include <hip/hip_runtime.h>
#include <hip/hip_bf16.h>
#include <cstdint>
#include <cstddef>

// ---------- types ----------
typedef __attribute__((ext_vector_type(4))) float f32x4;
typedef __attribute__((ext_vector_type(8))) short bf16x8;
typedef __attribute__((ext_vector_type(4))) int i32x4;
typedef void __attribute__((address_space(1)))* as1_void_p;
typedef void __attribute__((address_space(3)))* as3_void_p;

#define T_SEQ 2048
#define D_MODEL 2048
#define NUM_HEADS 32
#define NUM_KV 8
#define GROUPS 4
#define DK 64
#define WINDOW 512
#define BATCH 2

#define NEG_BIG (-30000.0f)

// fp32 -> bf16 round-to-nearest-even
__device__ __forceinline__ unsigned short f2b(float f) {
    unsigned int u = __builtin_bit_cast(unsigned int, f);
    u = (u + 0x7FFFu + ((u >> 16) & 1u)) >> 16;
    return (unsigned short)u;
}

// packed fp32x2 -> bf16x2 (single HW instruction; no builtin on gfx950)
__device__ __forceinline__ unsigned int cvtpk_bf16(float lo, float hi) {
    unsigned int r;
    asm("v_cvt_pk_bf16_f32 %0, %1, %2" : "=v"(r) : "v"(lo), "v"(hi));
    return r;
}

__device__ __forceinline__ void load_lds16(const void* g, void* l) {
    __builtin_amdgcn_global_load_lds((as1_void_p)(uintptr_t)g,
                                     (as3_void_p)(unsigned int)(uintptr_t)l,
                                     16, 0, 0);
}

// ---------- fused cast: all five fp32 inputs -> one contiguous bf16 region ----
#define CAST_N0 8388608
#define CAST_N1 12582912
#define CAST_N2 13631488
#define CAST_N3 14680064
#define CAST_N4 18874368
__global__ void cast_all_kernel(const float* __restrict__ x, const float* __restrict__ wq,
                                const float* __restrict__ wk, const float* __restrict__ wv,
                                const float* __restrict__ wo, unsigned short* __restrict__ dst) {
    int i = (blockIdx.x * blockDim.x + threadIdx.x) * 4;
    const int stride = gridDim.x * blockDim.x * 4;
    for (; i < CAST_N4; i += stride) {
        const float* src;
        int off;
        if (i < CAST_N0)      { src = x;  off = i; }
        else if (i < CAST_N1) { src = wq; off = i - CAST_N0; }
        else if (i < CAST_N2) { src = wk; off = i - CAST_N1; }
        else if (i < CAST_N3) { src = wv; off = i - CAST_N2; }
        else                  { src = wo; off = i - CAST_N3; }
        const float4 v = *(const float4*)(src + off);
        ushort4 o;
        o.x = f2b(v.x); o.y = f2b(v.y); o.z = f2b(v.z); o.w = f2b(v.w);
        *(ushort4*)(dst + i) = o;
    }
}

// ---------- RoPE cos/sin table: [T][32] ----------
__global__ void rope_table_kernel(float* __restrict__ ct, float* __restrict__ st) {
    int i = blockIdx.x * blockDim.x + threadIdx.x;  // T*32 = 65536 exact
    int t = i >> 5, j = i & 31;
    const float kln = 0.28782313662425556f;  // ln(10000)/32
    float inv = __expf(-(float)j * kln);
    if (j == 0) inv = 1.0f;
    float ang = (float)t * inv;
    float s, c;
    sincosf(ang, &s, &c);
    ct[i] = c; st[i] = s;
}

// ============================================================================
// QKV GEMM v3b: identical to R18 except the lgkmcnt(0)+sched_barrier pin
// between ds_reads and MFMAs is REMOVED (m141 lesson: order-pinning defeats
// the compiler's fine-grained lgkmcnt interleave; plain-load ds_reads are
// dependency-tracked, and in-order lgkm retirement means the compiler's
// auto-waits drain all reads before the end-of-tile barrier).
// ============================================================================
__global__ __launch_bounds__(512, 2) void gemm_qkv_rope(
    const unsigned short* __restrict__ A, const unsigned short* __restrict__ Bw,
    const float* __restrict__ ct, const float* __restrict__ st,
    unsigned short* __restrict__ Qb, unsigned short* __restrict__ Kb,
    unsigned short* __restrict__ Vt) {
    __shared__ __align__(16) unsigned short lds[65536];  // 128KB: 4 x (A 16KB + B 16KB)
    // bijective supertile decode for grid 192 = 8 xcd x 24
    const int bid = blockIdx.x;
    const int xcd = bid & 7;
    const int l = bid >> 3;            // 0..23
    const int stl = l >> 2;            // 0..5
    const int w = l & 3;
    const int tile_m = xcd * 2 + (w >> 1);   // 0..15
    const int tile_n = stl * 2 + (w & 1);    // 0..11

    const int tid = threadIdx.x;
    const int lane = tid & 63;
    const int wid = tid >> 6;
    const int wr = wid >> 2, wc = wid & 3;   // 2M x 4N
    const int lrow = lane & 15;
    const int g = lane >> 4;
    const int arow = tile_m * 256, brow = tile_n * 256;

    f32x4 acc[8][4] = {};

#define QSTAGE(SRC, ROWBASE, KCOL, USHOFF)                                     \
    { _Pragma("unroll") for (int u = 0; u < 2; ++u) {                          \
        const int gi = u * 512 + tid;                                          \
        const int row_ = gi >> 2, sl_ = gi & 3;                                \
        const int sc_ = (sl_ ^ ((row_ >> 1) & 3)) << 3;                        \
        load_lds16(SRC + (size_t)((ROWBASE) + row_) * 2048 + (KCOL) + sc_,     \
                   (char*)&lds[USHOFF] + gi * 16); } }

    QSTAGE(A, arow, 0,  0)     QSTAGE(Bw, brow, 0,  8192)
    QSTAGE(A, arow, 32, 16384) QSTAGE(Bw, brow, 32, 24576)
    QSTAGE(A, arow, 64, 32768) QSTAGE(Bw, brow, 64, 40960)
    asm volatile("s_waitcnt vmcnt(8)" ::: "memory");   // tile0's 4 loads landed
    __builtin_amdgcn_sched_barrier(0);
    __builtin_amdgcn_s_barrier();

    for (int t = 0; t < 64; ++t) {
        const int cb = (t & 3) * 16384;
        const int sb = ((t + 3) & 3) * 16384;
        bf16x8 af[8], bfr[4];
#pragma unroll
        for (int m = 0; m < 8; ++m) {
            const int R = wr * 128 + m * 16 + lrow;
            af[m] = *(const bf16x8*)&lds[cb + R * 32 + ((g ^ ((R >> 1) & 3)) << 3)];
        }
#pragma unroll
        for (int n = 0; n < 4; ++n) {
            const int R = wc * 64 + n * 16 + lrow;
            bfr[n] = *(const bf16x8*)&lds[cb + 8192 + R * 32 + ((g ^ ((R >> 1) & 3)) << 3)];
        }
        if (t + 3 < 64) {
            QSTAGE(A, arow, (t + 3) * 32, sb)
            QSTAGE(Bw, brow, (t + 3) * 32, sb + 8192)
        }
        // (no lgkmcnt pin: compiler interleaves ds_read waits with MFMAs)
        __builtin_amdgcn_s_setprio(1);
#pragma unroll
        for (int m = 0; m < 8; ++m)
#pragma unroll
            for (int n = 0; n < 4; ++n)
                acc[m][n] = __builtin_amdgcn_mfma_f32_16x16x32_bf16(af[m], bfr[n], acc[m][n], 0, 0, 0);
        __builtin_amdgcn_s_setprio(0);
        // counted wait: leave {t+2, t+3} in flight => t+1 landed
        if (t < 61)      { asm volatile("s_waitcnt vmcnt(8)" ::: "memory"); }
        else if (t == 61){ asm volatile("s_waitcnt vmcnt(4)" ::: "memory"); }
        else             { asm volatile("s_waitcnt vmcnt(0)" ::: "memory"); }
        __builtin_amdgcn_sched_barrier(0);
        __builtin_amdgcn_s_barrier();
    }
#undef QSTAGE

    // ---- fused epilogue: hcol = tile_n*4 + wc (64-col head block per wave) --
    const int hcol = tile_n * 4 + wc;     // 0..47
#pragma unroll
    for (int m = 0; m < 8; ++m) {
        const int row0 = tile_m * 256 + wr * 128 + m * 16 + g * 4;
        const int bb = row0 >> 11;
        const int t0 = row0 & 2047;
        if (hcol < 40) {
            const bool isQ = (hcol < 32);
            const float sc = isQ ? 0.125f : 1.0f;
            unsigned short* base = isQ
                ? (Qb + ((size_t)(bb * NUM_HEADS + hcol) * T_SEQ) * 64)
                : (Kb + ((size_t)(bb * NUM_KV + (hcol - 32)) * T_SEQ) * 64);
#pragma unroll
            for (int r = 0; r < 4; ++r) {
                const int t = t0 + r;
                unsigned short* dst = base + (size_t)t * 64;
#pragma unroll
                for (int n = 0; n < 2; ++n) {
                    const int j = n * 16 + lrow;
                    const float c = ct[t * 32 + j], s = st[t * 32 + j];
                    const float v0 = acc[m][n][r], v1 = acc[m][n + 2][r];
                    dst[j]      = f2b((v0 * c - v1 * s) * sc);
                    dst[j + 32] = f2b((v1 * c + v0 * s) * sc);
                }
            }
        } else {
            const int vh = hcol - 40;
            const int chunk = t0 >> 5, tk = t0 & 31;
            unsigned short* cbase = Vt + ((size_t)(bb * NUM_KV + vh) * 64 + chunk) * 2048 + tk;
#pragma unroll
            for (int n = 0; n < 4; ++n) {
                const int d = n * 16 + lrow;
                unsigned int u0 = cvtpk_bf16(acc[m][n][0], acc[m][n][1]);
                unsigned int u1 = cvtpk_bf16(acc[m][n][2], acc[m][n][3]);
                uint2 val; val.x = u0; val.y = u1;
                *(uint2*)(cbase + d * 32) = val;
            }
        }
    }
}

// ---------- out-proj GEMM (128x256, 8 waves 2Mx4N): fp32 out ----------------
__global__ __launch_bounds__(512, 2) void gemm_bf16_nt(
    const unsigned short* __restrict__ A, const unsigned short* __restrict__ B,
    float* __restrict__ C) {
    __shared__ __align__(16) unsigned short lds[49152];  // 96KB: 4 x (A4096 + B8192)
    const int bid = blockIdx.x;
    const int xcd = bid & 7;
    const int l = bid >> 3;            // 0..31
    const int stl = l >> 4;            // 0..1
    const int w = l & 15;
    const int tmD = xcd * 4 + (w >> 2);    // 0..31
    const int tnD = stl * 4 + (w & 3);     // 0..7

    const int tid = threadIdx.x;
    const int lane = tid & 63;
    const int wid = tid >> 6;
    const int wr = wid >> 2, wc = wid & 3;   // 2M x 4N
    const int lrow = lane & 15;
    const int g = lane >> 4;
    const int tile_m = tmD, tile_n = tnD;
    const int arow = tile_m * 128, brow = tile_n * 256;

    const int srow = tid >> 2, sslot = tid & 3;
    const int scol = (sslot ^ ((srow >> 1) & 3)) << 3;

    f32x4 acc[4][4] = {};

#define OSTAGE(BUF, KCOL)                                                      \
    {                                                                          \
        load_lds16(A + (size_t)(arow + srow) * 2048 + (KCOL) + scol,           \
                   (char*)&lds[(BUF) * 12288] + tid * 16);                     \
        _Pragma("unroll") for (int u = 0; u < 2; ++u) {                        \
            const int gi = u * 512 + tid;                                      \
            const int br_ = gi >> 2, bs_ = gi & 3;                             \
            const int bc_ = (bs_ ^ ((br_ >> 1) & 3)) << 3;                     \
            load_lds16(B + (size_t)(brow + br_) * 2048 + (KCOL) + bc_,         \
                       (char*)&lds[(BUF) * 12288 + 4096] + gi * 16);           \
        }                                                                      \
    }

    OSTAGE(0, 0) OSTAGE(1, 32) OSTAGE(2, 64)
    asm volatile("s_waitcnt vmcnt(6)" ::: "memory");
    __builtin_amdgcn_sched_barrier(0);
    __builtin_amdgcn_s_barrier();

    for (int t = 0; t < 64; ++t) {
        const int cb = (t & 3) * 12288;
        const int sb = (t + 3) & 3;
        bf16x8 af[4], bfr[4];
#pragma unroll
        for (int m = 0; m < 4; ++m) {
            const int R = wr * 64 + m * 16 + lrow;
            af[m] = *(const bf16x8*)&lds[cb + R * 32 + ((g ^ ((R >> 1) & 3)) << 3)];
        }
#pragma unroll
        for (int n = 0; n < 4; ++n) {
            const int R = wc * 64 + n * 16 + lrow;
            bfr[n] = *(const bf16x8*)&lds[cb + 4096 + R * 32 + ((g ^ ((R >> 1) & 3)) << 3)];
        }
        if (t + 3 < 64) OSTAGE(sb, (t + 3) * 32)
        // (no lgkmcnt pin: compiler interleaves ds_read waits with MFMAs)
        __builtin_amdgcn_s_setprio(1);
#pragma unroll
        for (int m = 0; m < 4; ++m)
#pragma unroll
            for (int n = 0; n < 4; ++n)
                acc[m][n] = __builtin_amdgcn_mfma_f32_16x16x32_bf16(af[m], bfr[n], acc[m][n], 0, 0, 0);
        __builtin_amdgcn_s_setprio(0);
        if (t < 63) { asm volatile("s_waitcnt vmcnt(6)" ::: "memory"); }
        else        { asm volatile("s_waitcnt vmcnt(0)" ::: "memory"); }
        __builtin_amdgcn_sched_barrier(0);
        __builtin_amdgcn_s_barrier();
    }
#undef OSTAGE

#pragma unroll
    for (int m = 0; m < 4; ++m)
#pragma unroll
        for (int n = 0; n < 4; ++n) {
            const int col = tile_n * 256 + wc * 64 + n * 16 + lrow;
#pragma unroll
            for (int r = 0; r < 4; ++r) {
                const int row = tile_m * 128 + wr * 64 + m * 16 + g * 4 + r;
                C[(size_t)row * 2048 + col] = acc[m][n][r];
            }
        }
}

// ---------- flash attention v9b: LDS-shared K/V, ring-4, no lgkmcnt pin ------
__global__ __launch_bounds__(512, 4) void attn_kernel(
    const unsigned short* __restrict__ Qb, const unsigned short* __restrict__ Kb,
    const unsigned short* __restrict__ Vt, unsigned short* __restrict__ Oout) {
    __shared__ __align__(16) unsigned short lds[16384];   // 4 x (K 2048 + V 2048)
    const int tid = threadIdx.x;
    const int lane = tid & 63;
    const int wv = tid >> 6;
    const int g4 = wv & 3;             // head within GQA group
    const int tile = wv >> 2;          // 0: rows q0A.., 1: rows q0A+16..
    const int bid = blockIdx.x;
    const int kvh = bid & 7;
    const int b = (bid >> 3) & 1;
    const int band = 63 - (bid >> 4);  // heavy-first
    const int q0A = band * 32;
    const int q0w = q0A + tile * 16;
    const int h = kvh * 4 + g4;

    const int lq = lane & 15;
    const int g = lane >> 4;
    const int kq8 = g * 8;
    const int q = q0w + lq;

    const unsigned short* Qrow = Qb + ((size_t)((b * NUM_HEADS + h) * T_SEQ) + q) * 64;
    const bf16x8 qf0 = *(const bf16x8*)(Qrow + kq8);
    const bf16x8 qf1 = *(const bf16x8*)(Qrow + 32 + kq8);

    f32x4 acc[4] = {};
    float lrun = 0.0f;

    int kc_lo = q0A - (WINDOW - 1);
    if (kc_lo < 0) kc_lo = 0;
    kc_lo &= ~31;
    const int N = ((q0A - kc_lo) >> 5) + 1;   // chunks, 1..17

    const unsigned short* Kg = Kb + (size_t)(b * NUM_KV + kvh) * T_SEQ * 64
                                  + (size_t)kc_lo * 64;
    const unsigned short* Vg = Vt + (size_t)(b * NUM_KV + kvh) * 64 * T_SEQ
                                  + (size_t)(kc_lo >> 5) * 2048;

    const int perm = (lq >> 2) * 8 + (lq & 3);
#define SWZK(r) (((r & 3) | ((r >> 3) << 2)) & 7)
    const int koff0 = perm * 64 + ((g ^ SWZK(perm)) << 3);
    const int koff1 = perm * 64 + (((4 + g) ^ SWZK(perm)) << 3);
    const int perm4 = perm + 4;
    const int koff2 = perm4 * 64 + ((g ^ SWZK(perm4)) << 3);
    const int koff3 = perm4 * 64 + (((4 + g) ^ SWZK(perm4)) << 3);
    int voff[4];
#pragma unroll
    for (int nd = 0; nd < 4; ++nd)
        voff[nd] = 2048 + (nd * 16 + lq) * 32 + ((g ^ ((lq >> 1) & 3)) << 3);

#define STAGE(T, BUF)                                                          \
    {                                                                          \
        if (tid < 256) {                                                       \
            const int row_ = tid >> 3, ps = tid & 7;                           \
            const int ls = ps ^ SWZK(row_);                                    \
            load_lds16(Kg + (size_t)(T) * 2048 + row_ * 64 + ls * 8,           \
                       (char*)lds + (BUF) * 8192 + tid * 16);                  \
        } else {                                                               \
            const int gi = tid - 256;                                          \
            const int row_ = gi >> 2, ps = gi & 3;                             \
            const int ls = ps ^ ((row_ >> 1) & 3);                             \
            load_lds16(Vg + (size_t)(T) * 2048 + row_ * 32 + ls * 8,           \
                       (char*)lds + (BUF) * 8192 + 4096 + gi * 16);            \
        }                                                                      \
    }

    STAGE(0, 0)
    if (N > 1) STAGE(1, 1)
    if (N > 2) STAGE(2, 2)
    if (N > 2)      { asm volatile("s_waitcnt vmcnt(2)" ::: "memory"); }
    else if (N > 1) { asm volatile("s_waitcnt vmcnt(1)" ::: "memory"); }
    else            { asm volatile("s_waitcnt vmcnt(0)" ::: "memory"); }
    __builtin_amdgcn_sched_barrier(0);
    __builtin_amdgcn_s_barrier();

    for (int t = 0; t < N; ++t) {
        const int kb = (t & 3) * 4096;
        bf16x8 kf[4], vf[4];
        kf[0] = *(const bf16x8*)&lds[kb + koff0];
        kf[1] = *(const bf16x8*)&lds[kb + koff1];
        kf[2] = *(const bf16x8*)&lds[kb + koff2];
        kf[3] = *(const bf16x8*)&lds[kb + koff3];
#pragma unroll
        for (int nd = 0; nd < 4; ++nd) vf[nd] = *(const bf16x8*)&lds[kb + voff[nd]];
        if (t + 3 < N) STAGE(t + 3, (t + 3) & 3)
        // (no lgkmcnt pin: compiler schedules QK^T as kf arrive)

        const int kc = kc_lo + t * 32;
        f32x4 st2[2] = {};
        st2[0] = __builtin_amdgcn_mfma_f32_16x16x32_bf16(kf[0], qf0, st2[0], 0, 0, 0);
        st2[0] = __builtin_amdgcn_mfma_f32_16x16x32_bf16(kf[1], qf1, st2[0], 0, 0, 0);
        st2[1] = __builtin_amdgcn_mfma_f32_16x16x32_bf16(kf[2], qf0, st2[1], 0, 0, 0);
        st2[1] = __builtin_amdgcn_mfma_f32_16x16x32_bf16(kf[3], qf1, st2[1], 0, 0, 0);

        float s8[8];
#pragma unroll
        for (int tt = 0; tt < 2; ++tt)
#pragma unroll
            for (int r = 0; r < 4; ++r) s8[tt * 4 + r] = st2[tt][r];

        if (kc < q0w - 496 || kc > q0w - 31) {
#pragma unroll
            for (int i = 0; i < 8; ++i) {
                const int key = kc + g * 8 + ((i >> 2) << 2) + (i & 3);
                const int dist = q - key;
                if (dist < 0 || dist >= WINDOW) s8[i] = NEG_BIG;
            }
        }

        float p8[8];
        float ps = 0.0f;
#pragma unroll
        for (int i = 0; i < 8; ++i) {
            p8[i] = __expf(s8[i]);
            ps += p8[i];
        }
        lrun += ps;

        i32x4 pwi;
        pwi[0] = (int)cvtpk_bf16(p8[0], p8[1]);
        pwi[1] = (int)cvtpk_bf16(p8[2], p8[3]);
        pwi[2] = (int)cvtpk_bf16(p8[4], p8[5]);
        pwi[3] = (int)cvtpk_bf16(p8[6], p8[7]);
        const bf16x8 pw = __builtin_bit_cast(bf16x8, pwi);

#pragma unroll
        for (int nd = 0; nd < 4; ++nd)
            acc[nd] = __builtin_amdgcn_mfma_f32_16x16x32_bf16(vf[nd], pw, acc[nd], 0, 0, 0);

        if (t + 1 < N) {
            if (t + 3 < N)      { asm volatile("s_waitcnt vmcnt(2)" ::: "memory"); }
            else if (t + 2 < N) { asm volatile("s_waitcnt vmcnt(1)" ::: "memory"); }
            else                { asm volatile("s_waitcnt vmcnt(0)" ::: "memory"); }
            __builtin_amdgcn_sched_barrier(0);
            __builtin_amdgcn_s_barrier();
        }
    }
#undef STAGE
#undef SWZK

    lrun += __shfl_xor(lrun, 16);
    lrun += __shfl_xor(lrun, 32);

    const float inv = 1.0f / lrun;
#pragma unroll
    for (int nd = 0; nd < 4; ++nd) {
        unsigned int u0 = cvtpk_bf16(acc[nd][0] * inv, acc[nd][1] * inv);
        unsigned int u1 = cvtpk_bf16(acc[nd][2] * inv, acc[nd][3] * inv);
        unsigned short* dst = Oout + ((size_t)(b * T_SEQ + q)) * D_MODEL + h * 64 + nd * 16 + g * 4;
        uint2 val; val.x = u0; val.y = u1;
        *(uint2*)dst = val;
    }
}

// ---------- launch ----------
extern "C" void kernel_launch(void* const* d_in, const int* in_sizes, int n_in,
                              void* d_out, int out_size, void* d_ws, size_t ws_size,
                              hipStream_t stream) {
    const float* x = (const float*)d_in[0];
    const float* Wq = (const float*)d_in[1];
    const float* Wk = (const float*)d_in[2];
    const float* Wv = (const float*)d_in[3];
    const float* Wo = (const float*)d_in[4];
    float* out = (float*)d_out;

    char* ws = (char*)d_ws;
    size_t off = 0;
    auto alloc = [&](size_t bytes) -> char* {
        char* p = ws + off;
        off += (bytes + 255) & ~(size_t)255;
        return p;
    };
    // NOTE: xb, wcat, wob MUST stay contiguous in this order (cast_all_kernel
    // writes them as one linear region).
    unsigned short* xb   = (unsigned short*)alloc(8388608ull * 2);   // x bf16
    unsigned short* wcat = (unsigned short*)alloc(6291456ull * 2);   // [Wq;Wk;Wv]
    unsigned short* wob  = (unsigned short*)alloc(4194304ull * 2);   // Wo
    unsigned short* qb   = (unsigned short*)alloc(8388608ull * 2);   // [B][32][T][64]
    unsigned short* kb   = (unsigned short*)alloc(2097152ull * 2);   // [B][8][T][64]
    unsigned short* vt   = (unsigned short*)alloc(2097152ull * 2);   // [B][8][64 chunks][64][32]
    unsigned short* attn = (unsigned short*)alloc(8388608ull * 2);   // [4096][2048]
    float* ct            = (float*)alloc(65536ull * 4);
    float* st            = (float*)alloc(65536ull * 4);

    cast_all_kernel<<<2048, 256, 0, stream>>>(x, Wq, Wk, Wv, Wo, xb);
    rope_table_kernel<<<256, 256, 0, stream>>>(ct, st);

    // QKV projection + fused RoPE/relayout: [4096,2048] x [3072,2048]^T
    gemm_qkv_rope<<<192, 512, 0, stream>>>(xb, wcat, ct, st, qb, kb, vt);

    attn_kernel<<<1024, 512, 0, stream>>>(qb, kb, vt, attn);

    // output projection: [4096,2048] x [2048,2048]^T -> d_out fp32
    gemm_bf16_nt<<<256, 512, 0, stream>>>(attn, wob, out);
}